// Round 17
// baseline (646.732 us; speedup 1.0000x reference)
//
#include <hip/hip_runtime.h>
#include <stdint.h>

typedef unsigned short u16;
typedef __attribute__((ext_vector_type(8))) short short8;
typedef __attribute__((ext_vector_type(8))) u16 u16x8;
typedef __attribute__((ext_vector_type(4))) u16 u16x4;
typedef __attribute__((ext_vector_type(4))) float f32x4;

#define E_TOT 30000
#define TL    3712     // 29*128

// PERM: m-major reorder of the 29 (l,m) coefficients
__constant__ int d_PERM[29] = {0,2,6,11,16,21,26, 3,7,12,17,22,27, 1,5,10,15,20,25,
                               8,13,18,23,28, 4,9,14,19,24};
// inverse of RADCOL: for each 128-wide rad block, the 1-2 t-rows it feeds
__constant__ int d_RINV[18][2] = {
  {0,-1},{1,-1},{2,-1},{3,-1},{4,-1},{5,-1},{6,-1},
  {7,13},{8,14},{9,15},{10,16},{11,17},{12,18},
  {19,24},{20,25},{21,26},{22,27},{23,28}};

__device__ __forceinline__ u16 f2bf(float f){
  union { float f; uint32_t u; } v; v.f = f;
  return (u16)((v.u + 0x7FFFu + ((v.u >> 16) & 1u)) >> 16);   // RNE
}
__device__ __forceinline__ float bf2f(u16 u){
  union { uint32_t u; float f; } v; v.u = ((uint32_t)u) << 16;
  return v.f;
}
__device__ __forceinline__ void gl_lds16(const void* g, void* l){
  __builtin_amdgcn_global_load_lds((const __attribute__((address_space(1))) void*)g,
                                   (__attribute__((address_space(3))) void*)l, 16, 0, 0);
}

// ---------------------------------------------------------------- weights
__global__ void k_build_w(const float* __restrict__ w0, const float* __restrict__ w1,
                          const float* __restrict__ w2, const float* __restrict__ rw2,
                          u16* __restrict__ W0, u16* __restrict__ W1, u16* __restrict__ W2,
                          u16* __restrict__ w2b){
  int idx = blockIdx.x * 256 + threadIdx.x;
  if (idx < 2304*128){ w2b[idx] = f2bf(rw2[idx]); return; }
  idx -= 2304*128;
  if (idx < 1024*896){
    W0[idx] = (idx < 896*896) ? f2bf(w0[idx]) : (u16)0;
    return;
  }
  idx -= 1024*896;
  if (idx < 1536*1536){
    const int half = 768;
    int o = idx / 1536, i2 = idx - o*1536;
    float v;
    if (o < half) v = (i2 < half) ? w1[o*half + i2] : -w1[(half+o)*half + (i2-half)];
    else { int op = o - half;
           v = (i2 < half) ? w1[(half+op)*half + i2] : w1[op*half + (i2-half)]; }
    W1[idx] = f2bf(v);
    return;
  }
  idx -= 1536*1536;
  if (idx < 1280*1280){
    const int half = 640;
    int o = idx / 1280, i2 = idx - o*1280;
    float v;
    if (o < half) v = (i2 < half) ? w2[o*half + i2] : -w2[(half+o)*half + (i2-half)];
    else { int op = o - half;
           v = (i2 < half) ? w2[(half+op)*half + i2] : w2[op*half + (i2-half)]; }
    W2[idx] = f2bf(v);
  }
}

// ---------------------------------------------------------------- h = silu(LN(xe@w1^T+b1))
__global__ __launch_bounds__(256) void k_h(const float* __restrict__ xe,
    const float* __restrict__ w1, const float* __restrict__ b1,
    const float* __restrict__ g, const float* __restrict__ beta,
    u16* __restrict__ hout){
  __shared__ float sw[128*132];      // padded stride 132 (2-way-free banks)
  __shared__ float sxe[16*128];
  int tid = threadIdx.x;
  #pragma unroll
  for (int q = 0; q < 16; q++){
    int i4 = q*256 + tid;            // 4096 f32x4 chunks
    int row = i4 >> 5, c4 = (i4 & 31) * 4;
    *(f32x4*)&sw[row*132 + c4] = *(const f32x4*)&w1[row*128 + c4];
  }
  int el = tid >> 4, s = tid & 15;
  for (int g8 = 0; g8 < 8; g8++){
    long eb = (long)blockIdx.x * 128 + g8*16;
    if (eb >= E_TOT) break;
    __syncthreads();                 // WAR on sxe (and w1 visible on g8=0)
    #pragma unroll
    for (int q = 0; q < 2; q++){
      int off = q*1024 + tid*4;
      long er = eb + (off >> 7); if (er > (long)(E_TOT-1)) er = (long)(E_TOT-1);
      *(f32x4*)&sxe[off] = *(const f32x4*)&xe[er*128 + (off & 127)];
    }
    __syncthreads();
    float acc[8];
    #pragma unroll
    for (int q = 0; q < 8; q++) acc[q] = 0.f;
    const float* xr = &sxe[el*128];
    for (int c4 = 0; c4 < 32; c4++){
      f32x4 x = *(const f32x4*)&xr[c4*4];
      #pragma unroll
      for (int q = 0; q < 8; q++){
        f32x4 w = *(const f32x4*)&sw[(s + 16*q)*132 + c4*4];
        acc[q] += x[0]*w[0] + x[1]*w[1] + x[2]*w[2] + x[3]*w[3];
      }
    }
    float sum = 0.f, ss = 0.f;
    #pragma unroll
    for (int q = 0; q < 8; q++){
      acc[q] += b1[s + 16*q];
      sum += acc[q]; ss += acc[q]*acc[q];
    }
    #pragma unroll
    for (int m = 1; m < 16; m <<= 1){ sum += __shfl_xor(sum, m); ss += __shfl_xor(ss, m); }
    float mu = sum * (1.f/128.f);
    float var = ss * (1.f/128.f) - mu*mu;
    float rs = rsqrtf(var + 1e-5f);
    long e = eb + el;
    if (e < (long)E_TOT){
      #pragma unroll
      for (int q = 0; q < 8; q++){
        int j = s + 16*q;
        float v = (acc[q] - mu) * rs * g[j] + beta[j];
        v = v / (1.f + expf(-v));             // silu
        hout[e*128 + j] = f2bf(v);
      }
    }
  }
}

// ---------------------------------------------------------------- fused rad+t (R16 best)
__global__ __launch_bounds__(256) void k_radt(
    const u16* __restrict__ h, const u16* __restrict__ w2b,
    const float* __restrict__ b2, const float* __restrict__ xemb,
    u16* __restrict__ t)
{
  __shared__ u16 sH[64*136];
  __shared__ u16 sT[2][64*72];
  int tid = threadIdx.x;
  long eb = (long)blockIdx.x * 64;
  int nn0 = blockIdx.y * 4;
  #pragma unroll
  for (int q = 0; q < 4; q++){
    int ch = q*256 + tid;
    int row = ch >> 4, col = (ch & 15) * 8;
    long er = eb + row; if (er > (long)(E_TOT-1)) er = (long)(E_TOT-1);
    *(u16x8*)&sH[row*136 + col] = *(const u16x8*)&h[er*128 + col];
  }
  __syncthreads();
  int lane = tid & 63, wid = tid >> 6;
  int wr = wid >> 1, wc = wid & 1;        // wave grid 2x2, wave tile 32x32
  int lr = lane & 15, lh = lane >> 4;
  short8 afr[2][4];
  #pragma unroll
  for (int mi = 0; mi < 2; mi++)
    #pragma unroll
    for (int ks = 0; ks < 4; ks++)
      afr[mi][ks] = *(const short8*)&sH[(wr*32 + mi*16 + lr)*136 + ks*32 + lh*8];

  for (int nn = nn0; nn < nn0 + 4; ++nn){
    int p = nn & 1;
    int nb = nn * 64;
    f32x4 acc[2][2];
    #pragma unroll
    for (int mi = 0; mi < 2; mi++)
      #pragma unroll
      for (int nj = 0; nj < 2; nj++){ acc[mi][nj][0]=0;acc[mi][nj][1]=0;acc[mi][nj][2]=0;acc[mi][nj][3]=0; }
    #pragma unroll
    for (int ks = 0; ks < 4; ks++){
      #pragma unroll
      for (int nj = 0; nj < 2; nj++){
        short8 bf = *(const short8*)&w2b[(long)(nb + wc*32 + nj*16 + lr)*128 + ks*32 + lh*8];
        #pragma unroll
        for (int mi = 0; mi < 2; mi++)
          acc[mi][nj] = __builtin_amdgcn_mfma_f32_16x16x32_bf16(afr[mi][ks], bf, acc[mi][nj], 0, 0, 0);
      }
    }
    int rcb = nb >> 7, chalf = nb & 64;
    int nr = (d_RINV[rcb][1] >= 0) ? 2 : 1;
    f32x4 px0[2][2], px1[2][2];
    #pragma unroll
    for (int rr = 0; rr < 2; rr++){
      if (rr < nr){
        int xrow = d_PERM[d_RINV[rcb][rr]];
        #pragma unroll
        for (int q = 0; q < 2; q++){
          int ch = q*256 + tid;
          int row = ch >> 3, c8 = (ch & 7) * 8;
          long e = eb + row;
          if (e < (long)E_TOT){
            const float* xp = &xemb[(e*29 + xrow)*128 + chalf + c8];
            px0[rr][q] = *(const f32x4*)xp;
            px1[rr][q] = *(const f32x4*)(xp + 4);
          }
        }
      }
    }
    #pragma unroll
    for (int mi = 0; mi < 2; mi++){
      #pragma unroll
      for (int nj = 0; nj < 2; nj++){
        int col = wc*32 + nj*16 + lr;
        float bv = b2[nb + col];
        #pragma unroll
        for (int q = 0; q < 4; q++){
          int row = wr*32 + mi*16 + lh*4 + q;
          sT[p][row*72 + col] = f2bf(acc[mi][nj][q] + bv);
        }
      }
    }
    __syncthreads();
    #pragma unroll
    for (int rr = 0; rr < 2; rr++){
      if (rr < nr){
        int r = d_RINV[rcb][rr];
        #pragma unroll
        for (int q = 0; q < 2; q++){
          int ch = q*256 + tid;
          int row = ch >> 3, c8 = (ch & 7) * 8;
          long e = eb + row;
          if (e < (long)E_TOT){
            u16x8 rv = *(const u16x8*)&sT[p][row*72 + c8];
            u16x8 o;
            o[0]=f2bf(px0[rr][q][0]*bf2f(rv[0])); o[1]=f2bf(px0[rr][q][1]*bf2f(rv[1]));
            o[2]=f2bf(px0[rr][q][2]*bf2f(rv[2])); o[3]=f2bf(px0[rr][q][3]*bf2f(rv[3]));
            o[4]=f2bf(px1[rr][q][0]*bf2f(rv[4])); o[5]=f2bf(px1[rr][q][1]*bf2f(rv[5]));
            o[6]=f2bf(px1[rr][q][2]*bf2f(rv[6])); o[7]=f2bf(px1[rr][q][3]*bf2f(rv[7]));
            *(u16x8*)&t[(e*29 + r)*128 + chalf + c8] = o;
          }
        }
      }
    }
  }
}

// ---------------------------------------------------------------- anti-phase 256x128 GEMM
// 8 waves (4M x 2N, wave tile 64x64), 3-buffer LDS ring (3 x 48 KiB = 144 KiB,
// 1 block/CU, 2 waves/SIMD). Wave groups: G0 (wid<4) = READ(t) -> MFMA(t);
// G1 (wid>=4) = MFMA(t-1) -> READ(t). On each SIMD one G0 + one G1 wave run
// anti-phased, so the matrix pipe is fed during LDS-read bursts.
// Staging: tile t staged region t-2, validated vmcnt(6)+barrier region t-1,
// read region t, overwritten region t+1 (readers lgkm-drained before barrier).
#define WVM6 asm volatile("s_waitcnt vmcnt(6)" ::: "memory");
#define WVM0 asm volatile("s_waitcnt vmcnt(0)" ::: "memory");
#define LGK0 asm volatile("s_waitcnt lgkmcnt(0)" ::: "memory");
#define BARR __builtin_amdgcn_s_barrier();

#define STAGE(bufc)                                                           \
  { _Pragma("unroll")                                                         \
    for (int q = 0; q < 6; q++){                                              \
      gl_lds16(gsrc[q], S0 + (bufc)*24576 + ldso[q]);                         \
      gsrc[q] += 64;                                                          \
    } }

#define READT(bufc)                                                           \
  _Pragma("unroll")                                                           \
  for (int i = 0; i < 4; i++){                                                \
    _Pragma("unroll")                                                         \
    for (int ks = 0; ks < 2; ks++)                                            \
      af[i][ks] = *(const short8*)&S0[(bufc)*24576 +                          \
                    (wr*64 + i*16 + lr)*64 + ((ks*32 + lh*8) ^ swz)];         \
  }                                                                           \
  _Pragma("unroll")                                                           \
  for (int j = 0; j < 4; j++){                                                \
    _Pragma("unroll")                                                         \
    for (int ks = 0; ks < 2; ks++)                                            \
      bfr[j][ks] = *(const short8*)&S0[(bufc)*24576 + 16384 +                 \
                    (wc*64 + j*16 + lr)*64 + ((ks*32 + lh*8) ^ swz)];         \
  }

#define MFMA32                                                                \
  __builtin_amdgcn_s_setprio(1);                                              \
  _Pragma("unroll")                                                           \
  for (int ks = 0; ks < 2; ks++)                                              \
    _Pragma("unroll")                                                         \
    for (int i = 0; i < 4; i++)                                               \
      _Pragma("unroll")                                                       \
      for (int j = 0; j < 4; j++)                                             \
        acc[i][j] = __builtin_amdgcn_mfma_f32_16x16x32_bf16(                  \
            af[i][ks], bfr[j][ks], acc[i][j], 0, 0, 0);                       \
  __builtin_amdgcn_s_setprio(0);

// grid: 3422 = 118 panels(256 rows) x 29 n-tiles(128), n-inner; LPT order
// (W1 K=1536 first). Bijective XCD swizzle (3422 = 8*427 + 6).
__global__ __launch_bounds__(512, 2) void k_gemm(
    const u16* __restrict__ A,
    const u16* __restrict__ W0c, const u16* __restrict__ W1c, const u16* __restrict__ W2c,
    const float* __restrict__ bias0, float* __restrict__ out)
{
  __shared__ u16 S[3][24576];   // per buf: A [0,16384) (256x64), B [16384,24576) (128x64)
  u16* S0 = &S[0][0];

  int orig = blockIdx.x;
  int xcd = orig & 7, idxs = orig >> 3;
  int wgid = (xcd < 6 ? xcd*428 : 2568 + (xcd-6)*427) + idxs;

  int mi_ = wgid / 29, nidx = wgid - mi_*29;
  int mrow = mi_ * 256;
  int K, kbase, ncol, nvalid; const u16* Wg; const float* bias = nullptr;
  if (nidx < 12)      { K=1536; kbase=896;  Wg=W1c; ncol=nidx*128;      nvalid=1536; }
  else if (nidx < 22) { K=1280; kbase=2432; Wg=W2c; ncol=(nidx-12)*128; nvalid=1280; }
  else                { K=896;  kbase=0;    Wg=W0c; ncol=(nidx-22)*128; nvalid=896; bias=bias0; }
  int nkt = K >> 6;

  int tid = threadIdx.x;
  int lane = tid & 63, wid = tid >> 6;
  int wr = wid & 3, wc = wid >> 2;     // 4(M) x 2(N); G0 = wc 0 (wid<4), G1 = wc 1
  int lr = lane & 15, lh = lane >> 4;
  int swz = (lane & 7) << 3;

  // staging: 4 A-chunks + 2 B-chunks per thread (16B each), pre-swizzled source
  const u16* gsrc[6]; int ldso[6];
  #pragma unroll
  for (int q = 0; q < 4; q++){
    int CH = q*512 + tid;              // A: 256 rows x 8 chunks
    int row = CH >> 3, c16 = CH & 7;
    long e = mrow + row; if (e > (long)(E_TOT-1)) e = (long)(E_TOT-1);
    gsrc[q] = A + e*(long)TL + kbase + ((c16 ^ (row & 7)) << 3);
    ldso[q] = row*64 + c16*8;
  }
  #pragma unroll
  for (int q = 0; q < 2; q++){
    int CH = q*512 + tid;              // B: 128 rows x 8 chunks
    int row = CH >> 3, c16 = CH & 7;
    gsrc[4+q] = Wg + (long)(ncol + row)*K + ((c16 ^ (row & 7)) << 3);
    ldso[4+q] = 16384 + row*64 + c16*8;
  }

  f32x4 acc[4][4];
  #pragma unroll
  for (int i = 0; i < 4; i++)
    #pragma unroll
    for (int j = 0; j < 4; j++){ acc[i][j][0]=0;acc[i][j][1]=0;acc[i][j][2]=0;acc[i][j][3]=0; }

  short8 af[4][2];     // A fragments (G1 carries across one barrier)
  short8 bfr[4][2];    // B fragments

  // prologue: stage tile 0 -> buf 0, tile 1 -> buf 1 (12 loads); retire tile 0.
  STAGE(0)
  STAGE(1)
  WVM6
  BARR

  int bc = 0;          // buffer of tile t
  int bs = 2;          // buffer receiving tile t+2
  for (int t = 0; t < nkt; ++t){
    if (wid < 4){      // G0: consume-now
      READT(bc)
      MFMA32
    } else {           // G1: consume-later (frags from previous region)
      if (t > 0) { MFMA32 }
      READT(bc)
    }
    if (t + 2 < nkt){
      STAGE(bs)        // queue 6 -> 12
      WVM6             // retire tile t+1's 6 (issued one full region ago)
    } else if (t + 2 == nkt){
      WVM0             // drain tile nkt-1's 6
    }
    LGK0               // own ds_reads retired (WAR vs next region's staging)
    BARR
    bc = (bc == 2) ? 0 : bc + 1;
    bs = (bs == 2) ? 0 : bs + 1;
  }
  if (wid >= 4){ MFMA32 }   // G1 finishes tile nkt-1

  #pragma unroll
  for (int i = 0; i < 4; i++){
    #pragma unroll
    for (int j = 0; j < 4; j++){
      int col = wc*64 + j*16 + lr;
      if (ncol + col < nvalid){
        float bv = bias ? bias[ncol + col] : 0.f;
        #pragma unroll
        for (int q = 0; q < 4; q++){
          long row = mrow + wr*64 + i*16 + lh*4 + q;
          if (row < E_TOT)
            out[row*(long)TL + kbase + ncol + col] = acc[i][j][q] + bv;
        }
      }
    }
  }
}

extern "C" void kernel_launch(void* const* d_in, const int* in_sizes, int n_in,
                              void* d_out, int out_size, void* d_ws, size_t ws_size,
                              hipStream_t stream){
  (void)in_sizes; (void)n_in; (void)out_size;
  const float* x_emb  = (const float*)d_in[0];
  const float* x_edge = (const float*)d_in[1];
  const float* rad_w1 = (const float*)d_in[2];
  const float* rad_b1 = (const float*)d_in[3];
  const float* rad_g  = (const float*)d_in[4];
  const float* rad_bt = (const float*)d_in[5];
  const float* rad_w2 = (const float*)d_in[6];
  const float* rad_b2 = (const float*)d_in[7];
  const float* w_m0   = (const float*)d_in[8];
  const float* b_m0   = (const float*)d_in[9];
  const float* w_m1   = (const float*)d_in[10];
  const float* w_m2   = (const float*)d_in[11];
  float* out = (float*)d_out;
  char* ws = (char*)d_ws;

  // workspace layout (bytes, 16B-aligned)
  u16* t   = (u16*)(ws + 0);            // 30000*3712*2 = 222,720,000
  u16* h   = (u16*)(ws + 222720000);    // 30000*128*2  =   7,680,000
  u16* W0  = (u16*)(ws + 230400000);    // 1024*896*2   =   1,835,008
  u16* W1  = (u16*)(ws + 232235008);    // 1536*1536*2  =   4,718,592
  u16* W2  = (u16*)(ws + 236953600);    // 1280*1280*2  =   3,276,800
  u16* w2b = (u16*)(ws + 240230400);    // 2304*128*2   =     589,824
  if (ws_size < 240820224ull) return;

  k_build_w<<<dim3(20352), dim3(256), 0, stream>>>(w_m0, w_m1, w_m2, rad_w2,
                                                   W0, W1, W2, w2b);
  k_h<<<dim3(235), dim3(256), 0, stream>>>(x_edge, rad_w1, rad_b1, rad_g, rad_bt, h);
  k_radt<<<dim3(469, 9), dim3(256), 0, stream>>>(h, w2b, rad_b2, x_emb, t);
  k_gemm<<<dim3(3422), dim3(512), 0, stream>>>(t, W0, W1, W2, b_m0, out);
}

// Round 18
// 618.703 us; speedup vs baseline: 1.0453x; 1.0453x over previous
//
#include <hip/hip_runtime.h>
#include <stdint.h>

typedef unsigned short u16;
typedef __attribute__((ext_vector_type(8))) short short8;
typedef __attribute__((ext_vector_type(8))) u16 u16x8;
typedef __attribute__((ext_vector_type(4))) u16 u16x4;
typedef __attribute__((ext_vector_type(4))) float f32x4;

#define E_TOT 30000
#define TL    3712     // 29*128
#define BM    256
#define BK    64

// PERM: m-major reorder of the 29 (l,m) coefficients
__constant__ int d_PERM[29] = {0,2,6,11,16,21,26, 3,7,12,17,22,27, 1,5,10,15,20,25,
                               8,13,18,23,28, 4,9,14,19,24};
// inverse of RADCOL: for each 128-wide rad block, the 1-2 t-rows it feeds
__constant__ int d_RINV[18][2] = {
  {0,-1},{1,-1},{2,-1},{3,-1},{4,-1},{5,-1},{6,-1},
  {7,13},{8,14},{9,15},{10,16},{11,17},{12,18},
  {19,24},{20,25},{21,26},{22,27},{23,28}};

__device__ __forceinline__ u16 f2bf(float f){
  union { float f; uint32_t u; } v; v.f = f;
  return (u16)((v.u + 0x7FFFu + ((v.u >> 16) & 1u)) >> 16);   // RNE
}
__device__ __forceinline__ float bf2f(u16 u){
  union { uint32_t u; float f; } v; v.u = ((uint32_t)u) << 16;
  return v.f;
}
__device__ __forceinline__ void gl_lds16(const void* g, void* l){
  __builtin_amdgcn_global_load_lds((const __attribute__((address_space(1))) void*)g,
                                   (__attribute__((address_space(3))) void*)l, 16, 0, 0);
}

// ---------------------------------------------------------------- weights
// w2b = bf16(rad_w2); W0 [1024][896] (zero-padded rows); W1/W2 folded butterfly
__global__ void k_build_w(const float* __restrict__ w0, const float* __restrict__ w1,
                          const float* __restrict__ w2, const float* __restrict__ rw2,
                          u16* __restrict__ W0, u16* __restrict__ W1, u16* __restrict__ W2,
                          u16* __restrict__ w2b){
  int idx = blockIdx.x * 256 + threadIdx.x;
  if (idx < 2304*128){ w2b[idx] = f2bf(rw2[idx]); return; }
  idx -= 2304*128;
  if (idx < 1024*896){
    W0[idx] = (idx < 896*896) ? f2bf(w0[idx]) : (u16)0;
    return;
  }
  idx -= 1024*896;
  if (idx < 1536*1536){
    const int half = 768;
    int o = idx / 1536, i2 = idx - o*1536;
    float v;
    if (o < half) v = (i2 < half) ? w1[o*half + i2] : -w1[(half+o)*half + (i2-half)];
    else { int op = o - half;
           v = (i2 < half) ? w1[(half+op)*half + i2] : w1[op*half + (i2-half)]; }
    W1[idx] = f2bf(v);
    return;
  }
  idx -= 1536*1536;
  if (idx < 1280*1280){
    const int half = 640;
    int o = idx / 1280, i2 = idx - o*1280;
    float v;
    if (o < half) v = (i2 < half) ? w2[o*half + i2] : -w2[(half+o)*half + (i2-half)];
    else { int op = o - half;
           v = (i2 < half) ? w2[(half+op)*half + i2] : w2[op*half + (i2-half)]; }
    W2[idx] = f2bf(v);
  }
}

// ---------------------------------------------------------------- h = silu(LN(xe@w1^T+b1))
// w1 staged ONCE per block into padded LDS; 128 edges per block (8x16 groups).
__global__ __launch_bounds__(256) void k_h(const float* __restrict__ xe,
    const float* __restrict__ w1, const float* __restrict__ b1,
    const float* __restrict__ g, const float* __restrict__ beta,
    u16* __restrict__ hout){
  __shared__ float sw[128*132];      // padded stride 132 (2-way-free banks)
  __shared__ float sxe[16*128];
  int tid = threadIdx.x;
  #pragma unroll
  for (int q = 0; q < 16; q++){
    int i4 = q*256 + tid;            // 4096 f32x4 chunks
    int row = i4 >> 5, c4 = (i4 & 31) * 4;
    *(f32x4*)&sw[row*132 + c4] = *(const f32x4*)&w1[row*128 + c4];
  }
  int el = tid >> 4, s = tid & 15;
  for (int g8 = 0; g8 < 8; g8++){
    long eb = (long)blockIdx.x * 128 + g8*16;
    if (eb >= E_TOT) break;
    __syncthreads();                 // WAR on sxe (and w1 visible on g8=0)
    #pragma unroll
    for (int q = 0; q < 2; q++){
      int off = q*1024 + tid*4;
      long er = eb + (off >> 7); if (er > (long)(E_TOT-1)) er = (long)(E_TOT-1);
      *(f32x4*)&sxe[off] = *(const f32x4*)&xe[er*128 + (off & 127)];
    }
    __syncthreads();
    float acc[8];
    #pragma unroll
    for (int q = 0; q < 8; q++) acc[q] = 0.f;
    const float* xr = &sxe[el*128];
    for (int c4 = 0; c4 < 32; c4++){
      f32x4 x = *(const f32x4*)&xr[c4*4];
      #pragma unroll
      for (int q = 0; q < 8; q++){
        f32x4 w = *(const f32x4*)&sw[(s + 16*q)*132 + c4*4];
        acc[q] += x[0]*w[0] + x[1]*w[1] + x[2]*w[2] + x[3]*w[3];
      }
    }
    float sum = 0.f, ss = 0.f;
    #pragma unroll
    for (int q = 0; q < 8; q++){
      acc[q] += b1[s + 16*q];
      sum += acc[q]; ss += acc[q]*acc[q];
    }
    #pragma unroll
    for (int m = 1; m < 16; m <<= 1){ sum += __shfl_xor(sum, m); ss += __shfl_xor(ss, m); }
    float mu = sum * (1.f/128.f);
    float var = ss * (1.f/128.f) - mu*mu;
    float rs = rsqrtf(var + 1e-5f);
    long e = eb + el;
    if (e < (long)E_TOT){
      #pragma unroll
      for (int q = 0; q < 8; q++){
        int j = s + 16*q;
        float v = (acc[q] - mu) * rs * g[j] + beta[j];
        v = v / (1.f + expf(-v));             // silu
        hout[e*128 + j] = f2bf(v);
      }
    }
  }
}

// ---------------------------------------------------------------- fused rad+t
// sT double-buffered -> 1 barrier per nn; x_emb prefetched into regs before the
// barrier. y-grid split 9 ways (4 nn per block) for more latency-hiding blocks.
__global__ __launch_bounds__(256) void k_radt(
    const u16* __restrict__ h, const u16* __restrict__ w2b,
    const float* __restrict__ b2, const float* __restrict__ xemb,
    u16* __restrict__ t)
{
  __shared__ u16 sH[64*136];
  __shared__ u16 sT[2][64*72];
  int tid = threadIdx.x;
  long eb = (long)blockIdx.x * 64;
  int nn0 = blockIdx.y * 4;
  #pragma unroll
  for (int q = 0; q < 4; q++){
    int ch = q*256 + tid;
    int row = ch >> 4, col = (ch & 15) * 8;
    long er = eb + row; if (er > (long)(E_TOT-1)) er = (long)(E_TOT-1);
    *(u16x8*)&sH[row*136 + col] = *(const u16x8*)&h[er*128 + col];
  }
  __syncthreads();
  int lane = tid & 63, wid = tid >> 6;
  int wr = wid >> 1, wc = wid & 1;        // wave grid 2x2, wave tile 32x32
  int lr = lane & 15, lh = lane >> 4;
  short8 afr[2][4];
  #pragma unroll
  for (int mi = 0; mi < 2; mi++)
    #pragma unroll
    for (int ks = 0; ks < 4; ks++)
      afr[mi][ks] = *(const short8*)&sH[(wr*32 + mi*16 + lr)*136 + ks*32 + lh*8];

  for (int nn = nn0; nn < nn0 + 4; ++nn){
    int p = nn & 1;
    int nb = nn * 64;
    f32x4 acc[2][2];
    #pragma unroll
    for (int mi = 0; mi < 2; mi++)
      #pragma unroll
      for (int nj = 0; nj < 2; nj++){ acc[mi][nj][0]=0;acc[mi][nj][1]=0;acc[mi][nj][2]=0;acc[mi][nj][3]=0; }
    #pragma unroll
    for (int ks = 0; ks < 4; ks++){
      #pragma unroll
      for (int nj = 0; nj < 2; nj++){
        short8 bf = *(const short8*)&w2b[(long)(nb + wc*32 + nj*16 + lr)*128 + ks*32 + lh*8];
        #pragma unroll
        for (int mi = 0; mi < 2; mi++)
          acc[mi][nj] = __builtin_amdgcn_mfma_f32_16x16x32_bf16(afr[mi][ks], bf, acc[mi][nj], 0, 0, 0);
      }
    }
    int rcb = nb >> 7, chalf = nb & 64;
    int nr = (d_RINV[rcb][1] >= 0) ? 2 : 1;
    f32x4 px0[2][2], px1[2][2];
    #pragma unroll
    for (int rr = 0; rr < 2; rr++){
      if (rr < nr){
        int xrow = d_PERM[d_RINV[rcb][rr]];
        #pragma unroll
        for (int q = 0; q < 2; q++){
          int ch = q*256 + tid;
          int row = ch >> 3, c8 = (ch & 7) * 8;
          long e = eb + row;
          if (e < (long)E_TOT){
            const float* xp = &xemb[(e*29 + xrow)*128 + chalf + c8];
            px0[rr][q] = *(const f32x4*)xp;
            px1[rr][q] = *(const f32x4*)(xp + 4);
          }
        }
      }
    }
    #pragma unroll
    for (int mi = 0; mi < 2; mi++){
      #pragma unroll
      for (int nj = 0; nj < 2; nj++){
        int col = wc*32 + nj*16 + lr;
        float bv = b2[nb + col];
        #pragma unroll
        for (int q = 0; q < 4; q++){
          int row = wr*32 + mi*16 + lh*4 + q;
          sT[p][row*72 + col] = f2bf(acc[mi][nj][q] + bv);
        }
      }
    }
    __syncthreads();
    #pragma unroll
    for (int rr = 0; rr < 2; rr++){
      if (rr < nr){
        int r = d_RINV[rcb][rr];
        #pragma unroll
        for (int q = 0; q < 2; q++){
          int ch = q*256 + tid;
          int row = ch >> 3, c8 = (ch & 7) * 8;
          long e = eb + row;
          if (e < (long)E_TOT){
            u16x8 rv = *(const u16x8*)&sT[p][row*72 + c8];
            u16x8 o;
            o[0]=f2bf(px0[rr][q][0]*bf2f(rv[0])); o[1]=f2bf(px0[rr][q][1]*bf2f(rv[1]));
            o[2]=f2bf(px0[rr][q][2]*bf2f(rv[2])); o[3]=f2bf(px0[rr][q][3]*bf2f(rv[3]));
            o[4]=f2bf(px1[rr][q][0]*bf2f(rv[4])); o[5]=f2bf(px1[rr][q][1]*bf2f(rv[5]));
            o[6]=f2bf(px1[rr][q][2]*bf2f(rv[6])); o[7]=f2bf(px1[rr][q][3]*bf2f(rv[7]));
            *(u16x8*)&t[(e*29 + r)*128 + chalf + c8] = o;
          }
        }
      }
    }
  }
}

// ---------------------------------------------------------------- 256x256 GEMM, 2-sync/tile (best: R5/R12)
// LPT segment order: W1 (K=1536) first, then W2 (1280), then W0 (896).
#define WVM6 asm volatile("s_waitcnt vmcnt(6)" ::: "memory");
#define WVM2 asm volatile("s_waitcnt vmcnt(2)" ::: "memory");
#define WVM0 asm volatile("s_waitcnt vmcnt(0)" ::: "memory");
#define BARR __builtin_amdgcn_s_barrier();
#define SB0  __builtin_amdgcn_sched_barrier(0);

// read A-half QM into af (8 x ds_read_b128)
#define READ_A(buf, QM)                                                       \
  _Pragma("unroll")                                                           \
  for (int i = 0; i < 4; i++){                                                \
    _Pragma("unroll")                                                         \
    for (int ks = 0; ks < 2; ks++)                                            \
      af[i][ks] = *(const short8*)&S[buf][0][(wr*128 + (QM)*64 + i*16 + lr)*64\
                                            + ((ks*32 + lh*8) ^ swz)];        \
  }
// read B-half QN into dst (4 x ds_read_b128)
#define READ_B(dst, buf, QN)                                                  \
  _Pragma("unroll")                                                           \
  for (int j = 0; j < 2; j++){                                                \
    _Pragma("unroll")                                                         \
    for (int ks = 0; ks < 2; ks++)                                            \
      dst[j][ks] = *(const short8*)&S[buf][1][(wc*64 + (QN)*32 + j*16 + lr)*64\
                                              + ((ks*32 + lh*8) ^ swz)];      \
  }
// 16 MFMA for quadrant (QM,QN) using af x bfr
#define MFMA16(QM, QN, bfr)                                                   \
  __builtin_amdgcn_s_setprio(1);                                              \
  _Pragma("unroll")                                                           \
  for (int i = 0; i < 4; i++){                                                \
    _Pragma("unroll")                                                         \
    for (int j = 0; j < 2; j++){                                              \
      _Pragma("unroll")                                                       \
      for (int ks = 0; ks < 2; ks++)                                          \
        acc[(QM)*4+i][(QN)*2+j] = __builtin_amdgcn_mfma_f32_16x16x32_bf16(    \
            af[i][ks], bfr[j][ks], acc[(QM)*4+i][(QN)*2+j], 0, 0, 0);         \
    }                                                                         \
  }                                                                           \
  __builtin_amdgcn_s_setprio(0);

// staging: slots 0,1=B0  2,3=A0  4,5=B1  6,7=A1 (issue order == vmcnt order)
#define STAGE_EARLY(pn)                                                       \
  { _Pragma("unroll")                                                         \
    for (int k2 = 0; k2 < 6; k2++){                                           \
      gl_lds16(gsrc[k2], l0 + ((pn) << 15) + ldso[k2]);                       \
      gsrc[k2] += 64;                                                         \
    } }
#define STAGE_LATE(pn)                                                        \
  { _Pragma("unroll")                                                         \
    for (int k2 = 6; k2 < 8; k2++){                                           \
      gl_lds16(gsrc[k2], l0 + ((pn) << 15) + ldso[k2]);                       \
      gsrc[k2] += 64;                                                         \
    } }

// grid: 1770 blocks of 512 threads; 0..707 -> W1(K=1536), 708..1297 -> W2(1280),
// 1298..1769 -> W0(896). nbase == kbase for this problem.
__global__ __launch_bounds__(512, 2) void k_gemm8(
    const u16* __restrict__ A,
    const u16* __restrict__ W0, const u16* __restrict__ W1, const u16* __restrict__ W2,
    const float* __restrict__ bias0,
    float* __restrict__ out)
{
  __shared__ u16 S[2][2][BM*BK];   // [buf][A/B][256*64], swizzled (chunk ^= row&7)

  // bijective XCD swizzle over 1770 blocks, 8 XCDs (1770 = 8*221 + 2)
  int orig = blockIdx.x;
  int xcd = orig & 7, idxs = orig >> 3;
  int wgid = (xcd < 2 ? xcd*222 : 444 + (xcd-2)*221) + idxs;

  int ntn, K, kbase, nvalid, base;
  const u16* Wg; const float* bias = nullptr;
  if (wgid < 708)      { base=0;    ntn=6; K=1536; kbase=896;  nvalid=1536; Wg=W1; }
  else if (wgid < 1298){ base=708;  ntn=5; K=1280; kbase=2432; nvalid=1280; Wg=W2; }
  else                 { base=1298; ntn=4; K=896;  kbase=0;    nvalid=896;  Wg=W0; bias=bias0; }
  int local = wgid - base;
  int ncol = (local % ntn) * 256;
  int mrow = (local / ntn) * 256;
  int nkt  = K >> 6;

  int tid = threadIdx.x;
  int lane = tid & 63, wid = tid >> 6;
  int wr = wid >> 2, wc = wid & 3;     // wave grid 2(M) x 4(N); wave tile 128 x 64
  int lr = lane & 15, lh = lane >> 4;
  int swz = (lane & 7) << 3;           // read-side XOR (u16 units); row&7 == lane&7

  // hoisted staging addresses (per thread, advance +64 u16 per K-tile)
  const u16* gsrc[8];
  int ldso[8];
  u16* l0 = &S[0][0][0];
  #pragma unroll
  for (int j = 0; j < 2; j++){
    int CH = (wid*2 + j)*64 + lane;    // 1024 x 16B chunks per half-tile
    int c16 = CH & 7;
    int ra0 = ((CH >> 9) << 7) + ((CH >> 3) & 63);        // A0 rows {0-63,128-191}
    long g0 = mrow + ra0; if (g0 > (long)(E_TOT-1)) g0 = (long)(E_TOT-1);
    gsrc[2+j] = A + g0*(long)TL + kbase + ((c16 ^ (ra0 & 7)) << 3);
    ldso[2+j] = ra0*64 + c16*8;
    int ra1 = ra0 + 64;                                   // A1 rows {64-127,192-255}
    long g1 = mrow + ra1; if (g1 > (long)(E_TOT-1)) g1 = (long)(E_TOT-1);
    gsrc[6+j] = A + g1*(long)TL + kbase + ((c16 ^ (ra1 & 7)) << 3);
    ldso[6+j] = ra1*64 + c16*8;
    int rb0 = ((CH >> 8) << 6) + ((CH >> 3) & 31);        // B0 rows {+0..31 per 64-grp}
    gsrc[0+j] = Wg + (long)(ncol + rb0)*K + ((c16 ^ (rb0 & 7)) << 3);
    ldso[0+j] = 16384 + rb0*64 + c16*8;
    int rb1 = rb0 + 32;                                   // B1 rows {+32..63}
    gsrc[4+j] = Wg + (long)(ncol + rb1)*K + ((c16 ^ (rb1 & 7)) << 3);
    ldso[4+j] = 16384 + rb1*64 + c16*8;
  }

  f32x4 acc[8][4];
  #pragma unroll
  for (int i = 0; i < 8; i++)
    #pragma unroll
    for (int j = 0; j < 4; j++){ acc[i][j][0]=0;acc[i][j][1]=0;acc[i][j][2]=0;acc[i][j][3]=0; }

  short8 af[4][2];     // current A-half fragments
  short8 b0[2][2];     // B-half 0 (held across whole tile)
  short8 b1[2][2];     // B-half 1

  // prologue: stage tile 0 (B0,A0,B1 | A1) -> buf 0; retire first 6; read entry frags
  STAGE_EARLY(0)
  STAGE_LATE(0)
  WVM2 BARR SB0
  READ_A(0, 0)
  READ_B(b0, 0, 0)
  READ_B(b1, 0, 1)

  // steady state per tile: queue in = 2 (A1_t). Two sync points.
  for (int t = 0; t < nkt-1; ++t){
    int p = t & 1, pn = p ^ 1;
    STAGE_EARLY(pn)                   // B0,A0,B1 of t+1; queue 2 -> 8
    MFMA16(0,0,b0)
    MFMA16(0,1,b1)
    WVM6 BARR SB0                     // retire A1_t (cross-wave visible)
    READ_A(p, 1)
    STAGE_LATE(pn)                    // A1 of t+1; queue 6 -> 8
    MFMA16(1,1,b1)
    MFMA16(1,0,b0)
    WVM2 BARR SB0                     // retire B0,A0,B1 of t+1
    READ_A(pn, 0)
    READ_B(b0, pn, 0)
    READ_B(b1, pn, 1)
  }
  { // tail tile nkt-1 (buf p), queue in = 2 (its A1)
    int p = (nkt-1) & 1;
    MFMA16(0,0,b0)
    MFMA16(0,1,b1)
    WVM0 BARR SB0
    READ_A(p, 1)
    MFMA16(1,1,b1)
    MFMA16(1,0,b0)
  }

  #pragma unroll
  for (int mi = 0; mi < 8; mi++){
    #pragma unroll
    for (int nj = 0; nj < 4; nj++){
      int col = wc*64 + nj*16 + lr;
      if (ncol + col < nvalid){
        float bv = bias ? bias[ncol + col] : 0.f;
        #pragma unroll
        for (int q = 0; q < 4; q++){
          long row = mrow + wr*128 + mi*16 + lh*4 + q;
          if (row < E_TOT)
            out[row*(long)TL + kbase + ncol + col] = acc[mi][nj][q] + bv;
        }
      }
    }
  }
}

extern "C" void kernel_launch(void* const* d_in, const int* in_sizes, int n_in,
                              void* d_out, int out_size, void* d_ws, size_t ws_size,
                              hipStream_t stream){
  (void)in_sizes; (void)n_in; (void)out_size;
  const float* x_emb  = (const float*)d_in[0];
  const float* x_edge = (const float*)d_in[1];
  const float* rad_w1 = (const float*)d_in[2];
  const float* rad_b1 = (const float*)d_in[3];
  const float* rad_g  = (const float*)d_in[4];
  const float* rad_bt = (const float*)d_in[5];
  const float* rad_w2 = (const float*)d_in[6];
  const float* rad_b2 = (const float*)d_in[7];
  const float* w_m0   = (const float*)d_in[8];
  const float* b_m0   = (const float*)d_in[9];
  const float* w_m1   = (const float*)d_in[10];
  const float* w_m2   = (const float*)d_in[11];
  float* out = (float*)d_out;
  char* ws = (char*)d_ws;

  // workspace layout (bytes, 16B-aligned)
  u16* t   = (u16*)(ws + 0);            // 30000*3712*2 = 222,720,000
  u16* h   = (u16*)(ws + 222720000);    // 30000*128*2  =   7,680,000
  u16* W0  = (u16*)(ws + 230400000);    // 1024*896*2   =   1,835,008
  u16* W1  = (u16*)(ws + 232235008);    // 1536*1536*2  =   4,718,592
  u16* W2  = (u16*)(ws + 236953600);    // 1280*1280*2  =   3,276,800
  u16* w2b = (u16*)(ws + 240230400);    // 2304*128*2   =     589,824
  if (ws_size < 240820224ull) return;

  k_build_w<<<dim3(20352), dim3(256), 0, stream>>>(w_m0, w_m1, w_m2, rad_w2,
                                                   W0, W1, W2, w2b);
  k_h<<<dim3(235), dim3(256), 0, stream>>>(x_edge, rad_w1, rad_b1, rad_g, rad_bt, h);
  k_radt<<<dim3(469, 9), dim3(256), 0, stream>>>(h, w2b, rad_b2, x_emb, t);
  k_gemm8<<<dim3(1770), dim3(512), 0, stream>>>(t, W0, W1, W2, b_m0, out);
}